// Round 2
// baseline (607.858 us; speedup 1.0000x reference)
//
#include <hip/hip_runtime.h>
#include <stdint.h>

#define B_ 32
#define S_ 2048
#define D_ 1024

typedef __bf16 bf16x8 __attribute__((ext_vector_type(8)));
typedef float f32x4 __attribute__((ext_vector_type(4)));

__device__ __forceinline__ void gload_lds16(const void* g, void* l) {
  __builtin_amdgcn_global_load_lds(
      (const __attribute__((address_space(1))) void*)g,
      (__attribute__((address_space(3))) void*)l, 16, 0, 0);
}

// ---------------- zero score accumulator ----------------
__global__ void zero_scores_k(float4* p) {
  p[blockIdx.x * 256 + threadIdx.x] = make_float4(0.f, 0.f, 0.f, 0.f);
}

// ---------------- W2 transpose + bf16 convert: W2t[n][k] = W[D_+k][n] ----------------
__global__ __launch_bounds__(256) void conv_w2_k(const float* __restrict__ W,
                                                 unsigned short* __restrict__ W2t) {
  __shared__ float t[64][65];
  int k0 = blockIdx.x * 64, n0 = blockIdx.y * 64;
  int tx = threadIdx.x & 63, ty = threadIdx.x >> 6;  // ty 0..3
#pragma unroll
  for (int i = 0; i < 16; ++i) {
    int k = i * 4 + ty;
    t[k][tx] = W[(size_t)(D_ + k0 + k) * D_ + n0 + tx];
  }
  __syncthreads();
#pragma unroll
  for (int i = 0; i < 16; ++i) {
    int n = i * 4 + ty;
    __bf16 bv = (__bf16)t[tx][n];
    W2t[(size_t)(n0 + n) * D_ + k0 + tx] = *(unsigned short*)&bv;
  }
}

// ---------------- u[b][n] = hidden[b] @ W[:D] + bias ----------------
__global__ __launch_bounds__(256) void compute_u_k(const float* __restrict__ hidden,
                                                   const float* __restrict__ W,
                                                   const float* __restrict__ bias,
                                                   float* __restrict__ u) {
  __shared__ float h[D_];
  int b = blockIdx.x, nc = blockIdx.y;
  for (int i = threadIdx.x; i < D_; i += 256) h[i] = hidden[b * D_ + i];
  __syncthreads();
  int n = nc * 256 + threadIdx.x;
  float acc = bias[n];
#pragma unroll 8
  for (int k = 0; k < D_; ++k) acc = fmaf(h[k], W[(size_t)k * D_ + n], acc);
  u[b * D_ + n] = acc;
}

// ---------------- main fused GEMM: scores[b][s] += sum_n v[n]*tanh(enc@W2 + u) ----------------
// 128x128 tile, BK=32, 4 waves (2x2), 16x16x32 bf16 MFMA, double-buffered LDS.
__global__ __launch_bounds__(256) void bahdanau_gemm_k(
    const float* __restrict__ enc, const unsigned short* __restrict__ W2t,
    const float* __restrict__ u, const float* __restrict__ vvec,
    const int* __restrict__ src_len, float* __restrict__ scores) {
  __shared__ __align__(16) unsigned short As[2][4096];  // [128 rows][32 k] bf16, xor-swizzled
  __shared__ __align__(16) unsigned short Bs[2][4096];  // [128 n][32 k] bf16, xor-swizzled

  // XCD swizzle: all 8 n-blocks of one m-tile land on the same XCD (bid%8 == m%8)
  int bid = blockIdx.x;
  int mlow = bid & 7;
  int rem = bid >> 3;
  int nb = rem & 7;
  int mt = (rem >> 3) * 8 + mlow;  // 0..511
  int m0 = mt << 7;
  int n0 = nb << 7;
  int b = m0 >> 11;        // /S_
  int s0 = m0 & (S_ - 1);
  if (s0 >= src_len[b]) return;  // whole tile masked -> skip (uniform)

  int tid = threadIdx.x;
  int lane = tid & 63;
  int w = tid >> 6;
  int wm = (w >> 1) << 6;  // wave m offset: 0/64
  int wn = (w & 1) << 6;   // wave n offset: 0/64

  // A staging: thread t covers row t/2, k-half t%2 (16 floats -> 16 bf16 = 2x16B)
  int arow = tid >> 1, ahalf = tid & 1;
  const float* aptr = enc + (size_t)(m0 + arow) * D_ + ahalf * 16;
  int ac0 = ((ahalf << 1) | 0) ^ (arow & 3);
  int ac1 = ((ahalf << 1) | 1) ^ (arow & 3);

  // B staging: wave w stages segments 2w,2w+1 (16 n-rows each) via global_load_lds,
  // with source chunk pre-swizzled to match the read-side XOR.
  int seg0 = w << 1;
  int bn0 = (seg0 << 4) + (lane >> 2);
  int bn1 = bn0 + 16;
  int bc = (lane & 3) ^ (bn0 & 3);  // bn1 has same &3
  const unsigned short* bsrc0 = W2t + (size_t)(n0 + bn0) * D_ + bc * 8;
  const unsigned short* bsrc1 = W2t + (size_t)(n0 + bn1) * D_ + bc * 8;

  int lrow = lane & 15, lkc = lane >> 4;
  int fragoff = (wm + lrow) * 64 + ((lkc ^ (lrow & 3)) << 4);   // A frag byte offset
  int fragoffB = (wn + lrow) * 64 + ((lkc ^ (lrow & 3)) << 4);  // B frag byte offset

  float4 ar[4];
  f32x4 acc[4][4];
  f32x4 zero = {0.f, 0.f, 0.f, 0.f};
#pragma unroll
  for (int i = 0; i < 4; ++i)
#pragma unroll
    for (int j = 0; j < 4; ++j) acc[i][j] = zero;

  // prologue: stage kt=0 into buf 0
  {
    const float4* p = (const float4*)aptr;
    ar[0] = p[0]; ar[1] = p[1]; ar[2] = p[2]; ar[3] = p[3];
    gload_lds16(bsrc0, &Bs[0][seg0 << 9]);
    gload_lds16(bsrc1, &Bs[0][(seg0 + 1) << 9]);
    bf16x8 w0, w1;
    const float* f = (const float*)ar;
#pragma unroll
    for (int j = 0; j < 8; ++j) { w0[j] = (__bf16)f[j]; w1[j] = (__bf16)f[8 + j]; }
    *(bf16x8*)((char*)As[0] + arow * 64 + (ac0 << 4)) = w0;
    *(bf16x8*)((char*)As[0] + arow * 64 + (ac1 << 4)) = w1;
  }
  __syncthreads();

  int buf = 0;
  for (int kt = 0; kt < 32; ++kt) {
    if (kt < 31) {
      const float4* p = (const float4*)(aptr + (kt + 1) * 32);
      ar[0] = p[0]; ar[1] = p[1]; ar[2] = p[2]; ar[3] = p[3];
      gload_lds16(bsrc0 + (kt + 1) * 32, &Bs[buf ^ 1][seg0 << 9]);
      gload_lds16(bsrc1 + (kt + 1) * 32, &Bs[buf ^ 1][(seg0 + 1) << 9]);
    }
    const char* ab = (const char*)As[buf] + fragoff;
    const char* bb = (const char*)Bs[buf] + fragoffB;
    bf16x8 af[4], bfr[4];
#pragma unroll
    for (int i = 0; i < 4; ++i) af[i] = *(const bf16x8*)(ab + i * 1024);
#pragma unroll
    for (int i = 0; i < 4; ++i) bfr[i] = *(const bf16x8*)(bb + i * 1024);
#pragma unroll
    for (int i = 0; i < 4; ++i)
#pragma unroll
      for (int j = 0; j < 4; ++j)
        acc[i][j] = __builtin_amdgcn_mfma_f32_16x16x32_bf16(af[i], bfr[j], acc[i][j], 0, 0, 0);
    if (kt < 31) {
      bf16x8 w0, w1;
      const float* f = (const float*)ar;
#pragma unroll
      for (int j = 0; j < 8; ++j) { w0[j] = (__bf16)f[j]; w1[j] = (__bf16)f[8 + j]; }
      *(bf16x8*)((char*)As[buf ^ 1] + arow * 64 + (ac0 << 4)) = w0;
      *(bf16x8*)((char*)As[buf ^ 1] + arow * 64 + (ac1 << 4)) = w1;
    }
    __syncthreads();
    buf ^= 1;
  }

  // epilogue: z = acc + u[b][n]; e = tanh(z); partial[row] += v[n]*e; reduce over 16 lane-cols
  float uv[4], vv[4];
#pragma unroll
  for (int j = 0; j < 4; ++j) {
    int n = n0 + wn + j * 16 + lrow;
    uv[j] = u[(b << 10) + n];
    vv[j] = vvec[n];
  }
  float part[4][4];
#pragma unroll
  for (int i = 0; i < 4; ++i)
#pragma unroll
    for (int r = 0; r < 4; ++r) part[i][r] = 0.f;
#pragma unroll
  for (int i = 0; i < 4; ++i)
#pragma unroll
    for (int j = 0; j < 4; ++j)
#pragma unroll
      for (int r = 0; r < 4; ++r) {
        float z = acc[i][j][r] + uv[j];
        float e2 = __expf(2.0f * z);                               // v_exp
        float th = 1.0f - 2.0f * __builtin_amdgcn_rcpf(e2 + 1.0f); // tanh, safe at +-inf
        part[i][r] = fmaf(vv[j], th, part[i][r]);
      }
#pragma unroll
  for (int i = 0; i < 4; ++i)
#pragma unroll
    for (int r = 0; r < 4; ++r) {
      float s = part[i][r];
      s += __shfl_xor(s, 1, 64);
      s += __shfl_xor(s, 2, 64);
      s += __shfl_xor(s, 4, 64);
      s += __shfl_xor(s, 8, 64);
      if ((lane & 15) == 0) {
        int row = s0 + wm + i * 16 + ((lane >> 4) << 2) + r;
        atomicAdd(&scores[(b << 11) + row], s);
      }
    }
}

// ---------------- masked softmax over s < src_len ----------------
__global__ __launch_bounds__(256) void softmax_k(const float* __restrict__ scores,
                                                 const int* __restrict__ src_len,
                                                 float* __restrict__ out) {
  __shared__ float sc[S_];
  __shared__ float red[4];
  int b = blockIdx.x;
  int L = src_len[b];
  int tid = threadIdx.x;
  const float* row = scores + b * S_;
  float mx = -3.0e38f;
  for (int s = tid; s < S_; s += 256) {
    float val = (s < L) ? row[s] : -3.0e38f;
    sc[s] = val;
    mx = fmaxf(mx, val);
  }
#pragma unroll
  for (int off = 32; off >= 1; off >>= 1) mx = fmaxf(mx, __shfl_xor(mx, off, 64));
  if ((tid & 63) == 0) red[tid >> 6] = mx;
  __syncthreads();
  mx = fmaxf(fmaxf(red[0], red[1]), fmaxf(red[2], red[3]));
  __syncthreads();
  float sum = 0.f;
  for (int s = tid; s < S_; s += 256) {
    float e = (s < L) ? __expf(sc[s] - mx) : 0.f;
    sc[s] = e;
    sum += e;
  }
#pragma unroll
  for (int off = 32; off >= 1; off >>= 1) sum += __shfl_xor(sum, off, 64);
  if ((tid & 63) == 0) red[tid >> 6] = sum;
  __syncthreads();
  sum = red[0] + red[1] + red[2] + red[3];
  float inv = 1.0f / sum;
  for (int s = tid; s < S_; s += 256) out[b * S_ + s] = sc[s] * inv;
}

extern "C" void kernel_launch(void* const* d_in, const int* in_sizes, int n_in,
                              void* d_out, int out_size, void* d_ws, size_t ws_size,
                              hipStream_t stream) {
  const float* hidden = (const float*)d_in[0];
  const float* enc = (const float*)d_in[1];
  const float* W = (const float*)d_in[2];
  const float* bias = (const float*)d_in[3];
  const float* v = (const float*)d_in[4];
  const int* src_len = (const int*)d_in[5];
  float* out = (float*)d_out;

  char* ws = (char*)d_ws;
  float* scores = (float*)ws;                               // 256 KB
  float* u = (float*)(ws + 256 * 1024);                     // 128 KB
  unsigned short* W2t = (unsigned short*)(ws + 384 * 1024); // 2 MB

  zero_scores_k<<<dim3(64), dim3(256), 0, stream>>>((float4*)scores);
  conv_w2_k<<<dim3(16, 16), dim3(256), 0, stream>>>(W, W2t);
  compute_u_k<<<dim3(32, 4), dim3(256), 0, stream>>>(hidden, W, bias, u);
  bahdanau_gemm_k<<<dim3(4096), dim3(256), 0, stream>>>(enc, W2t, u, v, src_len, scores);
  softmax_k<<<dim3(32), dim3(256), 0, stream>>>(scores, src_len, out);
}

// Round 3
// 519.561 us; speedup vs baseline: 1.1699x; 1.1699x over previous
//
#include <hip/hip_runtime.h>
#include <stdint.h>

#define B_ 32
#define S_ 2048
#define D_ 1024

typedef __bf16 bf16x8 __attribute__((ext_vector_type(8)));
typedef float f32x4 __attribute__((ext_vector_type(4)));

__device__ __forceinline__ void gload_lds16(const void* g, void* l) {
  __builtin_amdgcn_global_load_lds(
      (const __attribute__((address_space(1))) void*)g,
      (__attribute__((address_space(3))) void*)l, 16, 0, 0);
}

// ---------------- zero scores (256KB) + u (128KB) ----------------
__global__ void zero_ws_k(float4* p) {
  p[blockIdx.x * 256 + threadIdx.x] = make_float4(0.f, 0.f, 0.f, 0.f);
}

// ---------------- W2 transpose + bf16 convert: W2t[n][k] = W[D_+k][n] ----------------
__global__ __launch_bounds__(256) void conv_w2_k(const float* __restrict__ W,
                                                 unsigned short* __restrict__ W2t) {
  __shared__ float t[64][65];
  int k0 = blockIdx.x * 64, n0 = blockIdx.y * 64;
  int tx = threadIdx.x & 63, ty = threadIdx.x >> 6;  // ty 0..3
#pragma unroll
  for (int i = 0; i < 16; ++i) {
    int k = i * 4 + ty;
    t[k][tx] = W[(size_t)(D_ + k0 + k) * D_ + n0 + tx];
  }
  __syncthreads();
#pragma unroll
  for (int i = 0; i < 16; ++i) {
    int n = i * 4 + ty;
    __bf16 bv = (__bf16)t[tx][n];
    W2t[(size_t)(n0 + n) * D_ + k0 + tx] = *(unsigned short*)&bv;
  }
}

// ---------------- enc fp32 -> bf16 (only chunks the gemm will read) ----------------
__global__ __launch_bounds__(256) void conv_enc_k(const float* __restrict__ enc,
                                                  unsigned short* __restrict__ encb,
                                                  const int* __restrict__ src_len) {
  int b = blockIdx.x, c = blockIdx.y;
  int s0 = c * 32;
  if (s0 >= src_len[b]) return;  // uniform skip; unread chunks stay poisoned (benign)
  size_t base = ((size_t)b * S_ + s0) * D_;
  const float4* src = (const float4*)(enc + base);
  bf16x8* dst = (bf16x8*)(encb + base);
#pragma unroll 4
  for (int i = threadIdx.x; i < 4096; i += 256) {
    float4 a = src[2 * i], bq = src[2 * i + 1];
    bf16x8 o;
    o[0] = (__bf16)a.x;  o[1] = (__bf16)a.y;  o[2] = (__bf16)a.z;  o[3] = (__bf16)a.w;
    o[4] = (__bf16)bq.x; o[5] = (__bf16)bq.y; o[6] = (__bf16)bq.z; o[7] = (__bf16)bq.w;
    dst[i] = o;
  }
}

// ---------------- u[b][n] += partial(hidden[b] @ W[:D]) + bias, split-K atomic ----------------
__global__ __launch_bounds__(256) void compute_u_k(const float* __restrict__ hidden,
                                                   const float* __restrict__ W,
                                                   const float* __restrict__ bias,
                                                   float* __restrict__ u) {
  __shared__ float h[256];
  int b = blockIdx.x, nc = blockIdx.y, kc = blockIdx.z;
  int tid = threadIdx.x;
  h[tid] = hidden[b * D_ + kc * 256 + tid];
  __syncthreads();
  int n = nc * 256 + tid;
  float acc = 0.f;
#pragma unroll 8
  for (int k = 0; k < 256; ++k)
    acc = fmaf(h[k], W[(size_t)(kc * 256 + k) * D_ + n], acc);
  if (kc == 0) acc += bias[n];
  atomicAdd(&u[b * D_ + n], acc);
}

// ================= PATH B: m97-structure bf16 GEMM (both operands via global_load_lds) ========
// 128x128 tile, BK=64, 4 waves (2x2), single-buffered LDS, 2 barriers/K-step.
__global__ __launch_bounds__(256) void bahdanau_gemm2_k(
    const unsigned short* __restrict__ encb, const unsigned short* __restrict__ W2t,
    const float* __restrict__ u, const float* __restrict__ vvec,
    const int* __restrict__ src_len, float* __restrict__ scores) {
  __shared__ __align__(16) unsigned short As[128 * 64];  // [row][k] linear
  __shared__ __align__(16) unsigned short Bs[128 * 64];  // [n][k] linear

  int bid = blockIdx.x;
  int mlow = bid & 7;
  int rem = bid >> 3;
  int nb = rem & 7;
  int mt = (rem >> 3) * 8 + mlow;
  int m0 = mt << 7;
  int n0 = nb << 7;
  int b = m0 >> 11;
  int s0 = m0 & (S_ - 1);
  if (s0 >= src_len[b]) return;

  int tid = threadIdx.x;
  int lane = tid & 63;
  int w = tid >> 6;
  int wm = (w >> 1) << 6;
  int wn = (w & 1) << 6;

  // staging: wave w covers rows w*32..w*32+31 (4 instrs of 8 rows); lane -> row(l>>3), kchunk(l&7)
  int srow = w * 32 + (lane >> 3);
  int scol = (lane & 7) * 8;
  const unsigned short* asrc = encb + (size_t)(m0 + srow) * D_ + scol;
  const unsigned short* bsrc = W2t + (size_t)(n0 + srow) * D_ + scol;

  int lrow = lane & 15, lkc = lane >> 4;

  f32x4 acc[4][4];
  f32x4 zero = {0.f, 0.f, 0.f, 0.f};
#pragma unroll
  for (int i = 0; i < 4; ++i)
#pragma unroll
    for (int j = 0; j < 4; ++j) acc[i][j] = zero;

  for (int kt = 0; kt < 16; ++kt) {
    __syncthreads();  // prior compute done before overwrite
#pragma unroll
    for (int q = 0; q < 4; ++q) {
      gload_lds16(asrc + kt * 64 + (size_t)q * 8 * D_, As + (w * 32 + q * 8) * 64);
      gload_lds16(bsrc + kt * 64 + (size_t)q * 8 * D_, Bs + (w * 32 + q * 8) * 64);
    }
    __syncthreads();  // vmcnt(0) drained here by compiler
#pragma unroll
    for (int ks = 0; ks < 2; ++ks) {
      bf16x8 af[4], bfr[4];
#pragma unroll
      for (int i = 0; i < 4; ++i)
        af[i] = *(const bf16x8*)(As + (wm + i * 16 + lrow) * 64 + ks * 32 + lkc * 8);
#pragma unroll
      for (int j = 0; j < 4; ++j)
        bfr[j] = *(const bf16x8*)(Bs + (wn + j * 16 + lrow) * 64 + ks * 32 + lkc * 8);
#pragma unroll
      for (int i = 0; i < 4; ++i)
#pragma unroll
        for (int j = 0; j < 4; ++j)
          acc[i][j] = __builtin_amdgcn_mfma_f32_16x16x32_bf16(af[i], bfr[j], acc[i][j], 0, 0, 0);
    }
  }

  float uv[4], vv[4];
#pragma unroll
  for (int j = 0; j < 4; ++j) {
    int n = n0 + wn + j * 16 + lrow;
    uv[j] = u[(b << 10) + n];
    vv[j] = vvec[n];
  }
  float part[4][4];
#pragma unroll
  for (int i = 0; i < 4; ++i)
#pragma unroll
    for (int r = 0; r < 4; ++r) part[i][r] = 0.f;
#pragma unroll
  for (int i = 0; i < 4; ++i)
#pragma unroll
    for (int j = 0; j < 4; ++j)
#pragma unroll
      for (int r = 0; r < 4; ++r) {
        float z = acc[i][j][r] + uv[j];
        float e2 = __expf(2.0f * z);
        float th = 1.0f - 2.0f * __builtin_amdgcn_rcpf(e2 + 1.0f);
        part[i][r] = fmaf(vv[j], th, part[i][r]);
      }
#pragma unroll
  for (int i = 0; i < 4; ++i)
#pragma unroll
    for (int r = 0; r < 4; ++r) {
      float s = part[i][r];
      s += __shfl_xor(s, 1, 64);
      s += __shfl_xor(s, 2, 64);
      s += __shfl_xor(s, 4, 64);
      s += __shfl_xor(s, 8, 64);
      if ((lane & 15) == 0) {
        int row = s0 + wm + i * 16 + ((lane >> 4) << 2) + r;
        atomicAdd(&scores[(b << 11) + row], s);
      }
    }
}

// ================= PATH A fallback: in-gemm fp32->bf16 convert (round-2 kernel) =============
__global__ __launch_bounds__(256) void bahdanau_gemm_k(
    const float* __restrict__ enc, const unsigned short* __restrict__ W2t,
    const float* __restrict__ u, const float* __restrict__ vvec,
    const int* __restrict__ src_len, float* __restrict__ scores) {
  __shared__ __align__(16) unsigned short As[2][4096];
  __shared__ __align__(16) unsigned short Bs[2][4096];
  int bid = blockIdx.x;
  int mlow = bid & 7;
  int rem = bid >> 3;
  int nb = rem & 7;
  int mt = (rem >> 3) * 8 + mlow;
  int m0 = mt << 7;
  int n0 = nb << 7;
  int b = m0 >> 11;
  int s0 = m0 & (S_ - 1);
  if (s0 >= src_len[b]) return;
  int tid = threadIdx.x;
  int lane = tid & 63;
  int w = tid >> 6;
  int wm = (w >> 1) << 6;
  int wn = (w & 1) << 6;
  int arow = tid >> 1, ahalf = tid & 1;
  const float* aptr = enc + (size_t)(m0 + arow) * D_ + ahalf * 16;
  int ac0 = ((ahalf << 1) | 0) ^ (arow & 3);
  int ac1 = ((ahalf << 1) | 1) ^ (arow & 3);
  int seg0 = w << 1;
  int bn0 = (seg0 << 4) + (lane >> 2);
  int bn1 = bn0 + 16;
  int bc = (lane & 3) ^ (bn0 & 3);
  const unsigned short* bsrc0 = W2t + (size_t)(n0 + bn0) * D_ + bc * 8;
  const unsigned short* bsrc1 = W2t + (size_t)(n0 + bn1) * D_ + bc * 8;
  int lrow = lane & 15, lkc = lane >> 4;
  int fragoff = (wm + lrow) * 64 + ((lkc ^ (lrow & 3)) << 4);
  int fragoffB = (wn + lrow) * 64 + ((lkc ^ (lrow & 3)) << 4);
  float4 ar[4];
  f32x4 acc[4][4];
  f32x4 zero = {0.f, 0.f, 0.f, 0.f};
#pragma unroll
  for (int i = 0; i < 4; ++i)
#pragma unroll
    for (int j = 0; j < 4; ++j) acc[i][j] = zero;
  {
    const float4* p = (const float4*)aptr;
    ar[0] = p[0]; ar[1] = p[1]; ar[2] = p[2]; ar[3] = p[3];
    gload_lds16(bsrc0, &Bs[0][seg0 << 9]);
    gload_lds16(bsrc1, &Bs[0][(seg0 + 1) << 9]);
    bf16x8 w0, w1;
    const float* f = (const float*)ar;
#pragma unroll
    for (int j = 0; j < 8; ++j) { w0[j] = (__bf16)f[j]; w1[j] = (__bf16)f[8 + j]; }
    *(bf16x8*)((char*)As[0] + arow * 64 + (ac0 << 4)) = w0;
    *(bf16x8*)((char*)As[0] + arow * 64 + (ac1 << 4)) = w1;
  }
  __syncthreads();
  int buf = 0;
  for (int kt = 0; kt < 32; ++kt) {
    if (kt < 31) {
      const float4* p = (const float4*)(aptr + (kt + 1) * 32);
      ar[0] = p[0]; ar[1] = p[1]; ar[2] = p[2]; ar[3] = p[3];
      gload_lds16(bsrc0 + (kt + 1) * 32, &Bs[buf ^ 1][seg0 << 9]);
      gload_lds16(bsrc1 + (kt + 1) * 32, &Bs[buf ^ 1][(seg0 + 1) << 9]);
    }
    const char* ab = (const char*)As[buf] + fragoff;
    const char* bb = (const char*)Bs[buf] + fragoffB;
    bf16x8 af[4], bfr[4];
#pragma unroll
    for (int i = 0; i < 4; ++i) af[i] = *(const bf16x8*)(ab + i * 1024);
#pragma unroll
    for (int i = 0; i < 4; ++i) bfr[i] = *(const bf16x8*)(bb + i * 1024);
#pragma unroll
    for (int i = 0; i < 4; ++i)
#pragma unroll
      for (int j = 0; j < 4; ++j)
        acc[i][j] = __builtin_amdgcn_mfma_f32_16x16x32_bf16(af[i], bfr[j], acc[i][j], 0, 0, 0);
    if (kt < 31) {
      bf16x8 w0, w1;
      const float* f = (const float*)ar;
#pragma unroll
      for (int j = 0; j < 8; ++j) { w0[j] = (__bf16)f[j]; w1[j] = (__bf16)f[8 + j]; }
      *(bf16x8*)((char*)As[buf ^ 1] + arow * 64 + (ac0 << 4)) = w0;
      *(bf16x8*)((char*)As[buf ^ 1] + arow * 64 + (ac1 << 4)) = w1;
    }
    __syncthreads();
    buf ^= 1;
  }
  float uv[4], vv[4];
#pragma unroll
  for (int j = 0; j < 4; ++j) {
    int n = n0 + wn + j * 16 + lrow;
    uv[j] = u[(b << 10) + n];
    vv[j] = vvec[n];
  }
  float part[4][4];
#pragma unroll
  for (int i = 0; i < 4; ++i)
#pragma unroll
    for (int r = 0; r < 4; ++r) part[i][r] = 0.f;
#pragma unroll
  for (int i = 0; i < 4; ++i)
#pragma unroll
    for (int j = 0; j < 4; ++j)
#pragma unroll
      for (int r = 0; r < 4; ++r) {
        float z = acc[i][j][r] + uv[j];
        float e2 = __expf(2.0f * z);
        float th = 1.0f - 2.0f * __builtin_amdgcn_rcpf(e2 + 1.0f);
        part[i][r] = fmaf(vv[j], th, part[i][r]);
      }
#pragma unroll
  for (int i = 0; i < 4; ++i)
#pragma unroll
    for (int r = 0; r < 4; ++r) {
      float s = part[i][r];
      s += __shfl_xor(s, 1, 64);
      s += __shfl_xor(s, 2, 64);
      s += __shfl_xor(s, 4, 64);
      s += __shfl_xor(s, 8, 64);
      if ((lane & 15) == 0) {
        int row = s0 + wm + i * 16 + ((lane >> 4) << 2) + r;
        atomicAdd(&scores[(b << 11) + row], s);
      }
    }
}

// ---------------- masked softmax over s < src_len ----------------
__global__ __launch_bounds__(256) void softmax_k(const float* __restrict__ scores,
                                                 const int* __restrict__ src_len,
                                                 float* __restrict__ out) {
  __shared__ float sc[S_];
  __shared__ float red[4];
  int b = blockIdx.x;
  int L = src_len[b];
  int tid = threadIdx.x;
  const float* row = scores + b * S_;
  float mx = -3.0e38f;
  for (int s = tid; s < S_; s += 256) {
    float val = (s < L) ? row[s] : -3.0e38f;
    sc[s] = val;
    mx = fmaxf(mx, val);
  }
#pragma unroll
  for (int off = 32; off >= 1; off >>= 1) mx = fmaxf(mx, __shfl_xor(mx, off, 64));
  if ((tid & 63) == 0) red[tid >> 6] = mx;
  __syncthreads();
  mx = fmaxf(fmaxf(red[0], red[1]), fmaxf(red[2], red[3]));
  __syncthreads();
  float sum = 0.f;
  for (int s = tid; s < S_; s += 256) {
    float e = (s < L) ? __expf(sc[s] - mx) : 0.f;
    sc[s] = e;
    sum += e;
  }
#pragma unroll
  for (int off = 32; off >= 1; off >>= 1) sum += __shfl_xor(sum, off, 64);
  if ((tid & 63) == 0) red[tid >> 6] = sum;
  __syncthreads();
  sum = red[0] + red[1] + red[2] + red[3];
  float inv = 1.0f / sum;
  for (int s = tid; s < S_; s += 256) out[b * S_ + s] = sc[s] * inv;
}

extern "C" void kernel_launch(void* const* d_in, const int* in_sizes, int n_in,
                              void* d_out, int out_size, void* d_ws, size_t ws_size,
                              hipStream_t stream) {
  const float* hidden = (const float*)d_in[0];
  const float* enc = (const float*)d_in[1];
  const float* W = (const float*)d_in[2];
  const float* bias = (const float*)d_in[3];
  const float* v = (const float*)d_in[4];
  const int* src_len = (const int*)d_in[5];
  float* out = (float*)d_out;

  char* ws = (char*)d_ws;
  float* scores = (float*)ws;                                // 256 KB
  float* u = (float*)(ws + 256 * 1024);                      // 128 KB
  unsigned short* W2t = (unsigned short*)(ws + 384 * 1024);  // 2 MB
  unsigned short* encb = (unsigned short*)(ws + 4ull * 1024 * 1024);  // 128 MB
  const size_t need = 4ull * 1024 * 1024 + (size_t)B_ * S_ * D_ * 2;

  zero_ws_k<<<dim3(96), dim3(256), 0, stream>>>((float4*)scores);  // scores + u
  conv_w2_k<<<dim3(16, 16), dim3(256), 0, stream>>>(W, W2t);
  compute_u_k<<<dim3(32, 4, 4), dim3(256), 0, stream>>>(hidden, W, bias, u);
  if (ws_size >= need) {
    conv_enc_k<<<dim3(32, 64), dim3(256), 0, stream>>>(enc, encb, src_len);
    bahdanau_gemm2_k<<<dim3(4096), dim3(256), 0, stream>>>(encb, W2t, u, v, src_len, scores);
  } else {
    bahdanau_gemm_k<<<dim3(4096), dim3(256), 0, stream>>>(enc, W2t, u, v, src_len, scores);
  }
  softmax_k<<<dim3(32), dim3(256), 0, stream>>>(scores, src_len, out);
}